// Round 4
// baseline (579.637 us; speedup 1.0000x reference)
//
#include <hip/hip_runtime.h>

#define NN 100000
#define NE 1600000

static inline int cdiv(long long a, int b) { return (int)((a + b - 1) / b); }

// ======================= CSR build =======================================
__global__ void hist_kernel(const int* __restrict__ col, int* __restrict__ cnt, int E) {
    int e = blockIdx.x * blockDim.x + threadIdx.x;
    if (e < E) atomicAdd(&cnt[col[e]], 1);
}

__global__ void dinv_kernel(const int* __restrict__ cnt, float* __restrict__ dinv, int N) {
    int i = blockIdx.x * blockDim.x + threadIdx.x;
    if (i < N) dinv[i] = rsqrtf((float)cnt[i] + 1.0f);
}

// phase A: 256 thr/block, 512 elems/block; exclusive scan of (cnt+1) -> rowptr,
// block total -> bsum[b]
__global__ void scan_blocks(const int* __restrict__ cnt, int* __restrict__ rowptr,
                            int* __restrict__ bsum, int N) {
    int t = threadIdx.x;
    int base = blockIdx.x * 512;
    int i0 = base + 2 * t, i1 = i0 + 1;
    int v0 = (i0 < N) ? cnt[i0] + 1 : 0;   // +1: self-edge slot
    int v1 = (i1 < N) ? cnt[i1] + 1 : 0;
    int s = v0 + v1;
    int lane = t & 63, wv = t >> 6;
    int incl = s;
#pragma unroll
    for (int off = 1; off < 64; off <<= 1) {
        int u = __shfl_up(incl, off, 64);
        if (lane >= off) incl += u;
    }
    __shared__ int wtot[4];
    if (lane == 63) wtot[wv] = incl;
    __syncthreads();
    int woff = 0;
    for (int w = 0; w < wv; w++) woff += wtot[w];
    int excl = woff + incl - s;
    if (i0 < N) rowptr[i0] = excl;
    if (i1 < N) rowptr[i1] = excl + v0;
    if (t == 255) bsum[blockIdx.x] = woff + incl;
}

// phase B: exclusive scan of block sums (G <= 256), single block
__global__ void scan_bsums(int* __restrict__ bsum, int G) {
    int t = threadIdx.x;
    int v = (t < G) ? bsum[t] : 0;
    int lane = t & 63, wv = t >> 6;
    int incl = v;
#pragma unroll
    for (int off = 1; off < 64; off <<= 1) {
        int u = __shfl_up(incl, off, 64);
        if (lane >= off) incl += u;
    }
    __shared__ int wtot[4];
    if (lane == 63) wtot[wv] = incl;
    __syncthreads();
    int woff = 0;
    for (int w = 0; w < wv; w++) woff += wtot[w];
    if (t < G) bsum[t] = woff + incl - v;
}

// phase C: add block offsets, prefill self-edge, init cursor past it
__global__ void scan_finish(int* __restrict__ rowptr, const int* __restrict__ bsum,
                            int* __restrict__ cursor, int* __restrict__ csr_row, int N) {
    int i = blockIdx.x * blockDim.x + threadIdx.x;
    if (i < N) {
        int v = rowptr[i] + bsum[i >> 9];
        rowptr[i] = v;
        csr_row[v] = i;        // self edge first in each segment
        cursor[i] = v + 1;
    }
    if (i == 0) rowptr[N] = NE + NN;
}

__global__ void fill_csr_kernel(const int* __restrict__ row, const int* __restrict__ col,
                                int* __restrict__ cursor, int* __restrict__ csr_row, int E) {
    int e = blockIdx.x * blockDim.x + threadIdx.x;
    if (e >= E) return;
    int c = col[e];
    int r = row[e];
    int pos = atomicAdd(&cursor[c], 1);
    csr_row[pos] = r;
}

// ======================= x pad copy (21 -> stride 24) ====================
__global__ void padx_kernel(const float* __restrict__ x, float* __restrict__ xp, int N) {
    int idx = blockIdx.x * blockDim.x + threadIdx.x;
    if (idx >= N * 21) return;
    int n = idx / 21;
    int k = idx - n * 21;
    xp[n * 24 + k] = x[idx];
}

// ======================= pull gather (float4 rows) =======================
// row stride in floats = 4*LPN. blockDim = (LPN, NPB). weight = dinv[r]*dinv[node].
// Self-edge is inside the CSR segment, so no separate self term.
template <int LPN, bool BIAS, bool STORE21>
__global__ void gather4_kernel(const float4* __restrict__ h, const int* __restrict__ rowptr,
                               const int* __restrict__ csr_row, const float* __restrict__ dinv,
                               const float* __restrict__ bias, float* __restrict__ outp, int N) {
    int node = blockIdx.x * blockDim.y + threadIdx.y;
    if (node >= N) return;
    int l = threadIdx.x;
    int s = rowptr[node], e = rowptr[node + 1];
    float dn = dinv[node];
    float4 acc = make_float4(0.f, 0.f, 0.f, 0.f);
    int i = s;
    for (; i + 1 < e; i += 2) {
        int r0 = csr_row[i];
        int r1 = csr_row[i + 1];
        float w0 = dinv[r0] * dn;
        float w1 = dinv[r1] * dn;
        float4 a = h[(size_t)r0 * LPN + l];
        float4 c = h[(size_t)r1 * LPN + l];
        acc.x = fmaf(w0, a.x, acc.x); acc.y = fmaf(w0, a.y, acc.y);
        acc.z = fmaf(w0, a.z, acc.z); acc.w = fmaf(w0, a.w, acc.w);
        acc.x = fmaf(w1, c.x, acc.x); acc.y = fmaf(w1, c.y, acc.y);
        acc.z = fmaf(w1, c.z, acc.z); acc.w = fmaf(w1, c.w, acc.w);
    }
    if (i < e) {
        int r0 = csr_row[i];
        float w0 = dinv[r0] * dn;
        float4 a = h[(size_t)r0 * LPN + l];
        acc.x = fmaf(w0, a.x, acc.x); acc.y = fmaf(w0, a.y, acc.y);
        acc.z = fmaf(w0, a.z, acc.z); acc.w = fmaf(w0, a.w, acc.w);
    }
    if (STORE21) {
        int j = 4 * l;
        float v[4] = {acc.x, acc.y, acc.z, acc.w};
#pragma unroll
        for (int c = 0; c < 4; c++) {
            int jj = j + c;
            if (jj < 21) outp[(size_t)node * 21 + jj] = v[c] + (BIAS ? bias[jj] : 0.f);
        }
    } else {
        ((float4*)outp)[(size_t)node * LPN + l] = acc;
    }
}

// ======================= register-tiled GEMM =============================
template <int FIN, int FOUT, int FOUTP, int NT, int RJ, bool BIAS, bool RELU,
          int XSTRIDE, int OSTRIDE>
__global__ void gemm_tiled(const float* __restrict__ x, const float* __restrict__ W,
                           const float* __restrict__ b, float* __restrict__ out, int N) {
    constexpr int JG = FOUTP / RJ;       // j-groups
    constexpr int NG = 256 / JG;         // node-groups
    constexpr int RN = NT / NG;          // nodes per thread
    constexpr int XLD = FIN + 1;         // padded LDS stride for x
    __shared__ float xs[NT * XLD];
    __shared__ float Ws[FIN * FOUTP];
    __shared__ float bs[FOUTP];
    const int t = threadIdx.x;
    const int node0 = blockIdx.x * NT;

    for (int i = t; i < FIN * FOUT; i += 256) {
        int k = i / FOUT;
        int j = i - k * FOUT;
        Ws[k * FOUTP + j] = W[i];
    }
    if (FOUTP > FOUT) {
        for (int i = t; i < FIN * (FOUTP - FOUT); i += 256) {
            int k = i / (FOUTP - FOUT);
            int j = i - k * (FOUTP - FOUT);
            Ws[k * FOUTP + FOUT + j] = 0.f;
        }
    }
    if (t < FOUTP) bs[t] = (BIAS && t < FOUT) ? b[t] : 0.f;

    if (FIN % 4 == 0) {
        constexpr int F4 = FIN / 4;
        for (int i = t; i < NT * F4; i += 256) {
            int n = i / F4;
            int kk = i - n * F4;
            int node = node0 + n;
            float4 v = (node < N) ? ((const float4*)x)[(size_t)node * (XSTRIDE / 4) + kk]
                                  : make_float4(0.f, 0.f, 0.f, 0.f);
            xs[n * XLD + 4 * kk + 0] = v.x;
            xs[n * XLD + 4 * kk + 1] = v.y;
            xs[n * XLD + 4 * kk + 2] = v.z;
            xs[n * XLD + 4 * kk + 3] = v.w;
        }
    } else {
        for (int i = t; i < NT * FIN; i += 256) {
            int n = i / FIN;
            int k = i - n * FIN;
            int node = node0 + n;
            xs[n * XLD + k] = (node < N) ? x[(size_t)node * XSTRIDE + k] : 0.f;
        }
    }
    __syncthreads();

    const int jg = t % JG;
    const int ng = t / JG;
    float acc[RN][RJ];
#pragma unroll
    for (int r = 0; r < RN; r++)
#pragma unroll
        for (int jj = 0; jj < RJ; jj++) acc[r][jj] = 0.f;

#pragma unroll 2
    for (int k = 0; k < FIN; k++) {
        float wv[RJ];
        if (RJ % 4 == 0) {
#pragma unroll
            for (int c = 0; c < RJ / 4; c++) {
                float4 w = *(const float4*)&Ws[k * FOUTP + jg * RJ + 4 * c];
                wv[4 * c + 0] = w.x; wv[4 * c + 1] = w.y;
                wv[4 * c + 2] = w.z; wv[4 * c + 3] = w.w;
            }
        } else {
#pragma unroll
            for (int c = 0; c < RJ / 2; c++) {
                float2 w = *(const float2*)&Ws[k * FOUTP + jg * RJ + 2 * c];
                wv[2 * c + 0] = w.x; wv[2 * c + 1] = w.y;
            }
        }
        float xv[RN];
#pragma unroll
        for (int r = 0; r < RN; r++) xv[r] = xs[(ng * RN + r) * XLD + k];
#pragma unroll
        for (int r = 0; r < RN; r++)
#pragma unroll
            for (int jj = 0; jj < RJ; jj++) acc[r][jj] = fmaf(xv[r], wv[jj], acc[r][jj]);
    }

#pragma unroll
    for (int r = 0; r < RN; r++) {
        int node = node0 + ng * RN + r;
        if (node >= N) continue;
        float* orow = out + (size_t)node * OSTRIDE + jg * RJ;
#pragma unroll
        for (int jj = 0; jj < RJ; jj++) {
            float v = acc[r][jj] + bs[jg * RJ + jj];
            if (RELU) v = fmaxf(v, 0.f);
            acc[r][jj] = v;
        }
        if (RJ % 4 == 0 && OSTRIDE % 4 == 0) {
#pragma unroll
            for (int c = 0; c < RJ / 4; c++) {
                *(float4*)&orow[4 * c] =
                    make_float4(acc[r][4 * c], acc[r][4 * c + 1], acc[r][4 * c + 2], acc[r][4 * c + 3]);
            }
        } else {
#pragma unroll
            for (int jj = 0; jj < RJ; jj++) orow[jj] = acc[r][jj];
        }
    }
}

// ======================= launch ==========================================
extern "C" void kernel_launch(void* const* d_in, const int* in_sizes, int n_in,
                              void* d_out, int out_size, void* d_ws, size_t ws_size,
                              hipStream_t stream) {
    const float* x  = (const float*)d_in[0];
    const int*   ei = (const int*)d_in[1];
    const float* W1 = (const float*)d_in[2]; const float* b1 = (const float*)d_in[3];
    const float* W2 = (const float*)d_in[4]; const float* b2 = (const float*)d_in[5];
    const float* W3 = (const float*)d_in[6]; const float* b3 = (const float*)d_in[7];
    const float* W4 = (const float*)d_in[8]; const float* b4 = (const float*)d_in[9];
    const int* row = ei;
    const int* col = ei + NE;
    float* out = (float*)d_out;

    // workspace layout (floats)
    float* A      = (float*)d_ws;                  // N x 128
    float* B      = A + (size_t)NN * 128;          // N x 128 (also padded-x staging)
    float* dinv   = B + (size_t)NN * 128;          // N
    int*   cnt    = (int*)(dinv + NN);             // N
    int*   rowptr = cnt + NN;                      // N+1
    int*   cursor = rowptr + NN + 1;               // N
    int*   csr_row= cursor + NN;                   // E + N
    int*   bsum   = csr_row + NE + NN;             // 256

    const int BS = 256;
    const int SCAN_G = cdiv(NN, 512);  // 196

    // ---- CSR + dinv ----
    hipMemsetAsync(cnt, 0, NN * sizeof(int), stream);
    hist_kernel<<<cdiv(NE, BS), BS, 0, stream>>>(col, cnt, NE);
    dinv_kernel<<<cdiv(NN, BS), BS, 0, stream>>>(cnt, dinv, NN);
    scan_blocks<<<SCAN_G, 256, 0, stream>>>(cnt, rowptr, bsum, NN);
    scan_bsums<<<1, 256, 0, stream>>>(bsum, SCAN_G);
    scan_finish<<<cdiv(NN, BS), BS, 0, stream>>>(rowptr, bsum, cursor, csr_row, NN);
    fill_csr_kernel<<<cdiv(NE, BS), BS, 0, stream>>>(row, col, cursor, csr_row, NE);

    // ---- pad x into B (stride 24) ----
    padx_kernel<<<cdiv((long long)NN * 21, BS), BS, 0, stream>>>(x, B, NN);

    // ---- Layer 1: gather(x24) [B->A], gemm 21->32 +b relu [A->B, stride 32] ----
    {
        dim3 blk(6, 42);
        gather4_kernel<6, false, false><<<cdiv(NN, 42), blk, 0, stream>>>(
            (const float4*)B, rowptr, csr_row, dinv, nullptr, A, NN);
        gemm_tiled<21, 32, 32, 64, 8, true, true, 24, 32><<<cdiv(NN, 64), 256, 0, stream>>>(
            A, W1, b1, B, NN);
    }
    // ---- Layer 2: gather(h1) [B->A], gemm 32->64 +b relu [A->B, stride 64] ----
    {
        dim3 blk(8, 32);
        gather4_kernel<8, false, false><<<cdiv(NN, 32), blk, 0, stream>>>(
            (const float4*)B, rowptr, csr_row, dinv, nullptr, A, NN);
        gemm_tiled<32, 64, 64, 64, 8, true, true, 32, 64><<<cdiv(NN, 64), 256, 0, stream>>>(
            A, W2, b2, B, NN);
    }
    // ---- Layer 3: gather(h2) [B->A], gemm 64->128 +b relu [A->B, stride 128] ----
    {
        dim3 blk(16, 16);
        gather4_kernel<16, false, false><<<cdiv(NN, 16), blk, 0, stream>>>(
            (const float4*)B, rowptr, csr_row, dinv, nullptr, A, NN);
        gemm_tiled<64, 128, 128, 64, 8, true, true, 64, 128><<<cdiv(NN, 64), 256, 0, stream>>>(
            A, W3, b3, B, NN);
    }
    // ---- Layer 4: gemm 128->21 [B->A, stride 24], gather+b4 [A->out, stride 21] ----
    {
        gemm_tiled<128, 21, 24, 64, 6, false, false, 128, 24><<<cdiv(NN, 64), 256, 0, stream>>>(
            B, W4, nullptr, A, NN);
        dim3 blk(6, 42);
        gather4_kernel<6, true, true><<<cdiv(NN, 42), blk, 0, stream>>>(
            (const float4*)A, rowptr, csr_row, dinv, b4, out, NN);
    }
}

// Round 5
// 438.361 us; speedup vs baseline: 1.3223x; 1.3223x over previous
//
#include <hip/hip_runtime.h>

#define NN 100000
#define NE 1600000
#define SH 7
#define NB_BKT 782        // ceil(100000/128)
#define CHUNK 8192

static inline int cdiv(long long a, int b) { return (int)((a + b - 1) / b); }

// ======================= bucketed CSR build ==============================
// P1: per-chunk LDS histogram of buckets -> global bucket counts
__global__ void bucket_hist(const int* __restrict__ col, int* __restrict__ bcnt, int E) {
    __shared__ int lh[NB_BKT];
    for (int i = threadIdx.x; i < NB_BKT; i += 256) lh[i] = 0;
    __syncthreads();
    int base = blockIdx.x * CHUNK;
    int end = min(base + CHUNK, E);
    for (int e = base + threadIdx.x; e < end; e += 256) atomicAdd(&lh[col[e] >> SH], 1);
    __syncthreads();
    for (int i = threadIdx.x; i < NB_BKT; i += 256)
        if (lh[i]) atomicAdd(&bcnt[i], lh[i]);
}

// P2: single-block exclusive scan of bucket counts (NB_BKT <= 1024)
__global__ void bucket_scan(const int* __restrict__ bcnt, int* __restrict__ bptr,
                            int* __restrict__ bcur) {
    int t = threadIdx.x;
    int v[4];
    int base = 4 * t;
    int s = 0;
#pragma unroll
    for (int c = 0; c < 4; c++) {
        int i = base + c;
        v[c] = (i < NB_BKT) ? bcnt[i] : 0;
        s += v[c];
    }
    int lane = t & 63, wv = t >> 6;
    int incl = s;
#pragma unroll
    for (int off = 1; off < 64; off <<= 1) {
        int u = __shfl_up(incl, off, 64);
        if (lane >= off) incl += u;
    }
    __shared__ int wtot[4];
    if (lane == 63) wtot[wv] = incl;
    __syncthreads();
    int woff = 0;
    for (int w = 0; w < wv; w++) woff += wtot[w];
    int excl = woff + incl - s;
#pragma unroll
    for (int c = 0; c < 4; c++) {
        int i = base + c;
        if (i < NB_BKT) { bptr[i] = excl; bcur[i] = excl; }
        excl += v[c];
    }
    if (t == 255) bptr[NB_BKT] = woff + incl;   // == NE
}

// P3: partition edges into bucket-contiguous packed (col,row) u64 array
__global__ void partition_kernel(const int* __restrict__ row, const int* __restrict__ col,
                                 int* __restrict__ bcur,
                                 unsigned long long* __restrict__ packed, int E) {
    __shared__ int lh[NB_BKT];
    __shared__ int lbase[NB_BKT];
    for (int i = threadIdx.x; i < NB_BKT; i += 256) lh[i] = 0;
    __syncthreads();
    int base = blockIdx.x * CHUNK;
    int end = min(base + CHUNK, E);
    for (int e = base + threadIdx.x; e < end; e += 256) atomicAdd(&lh[col[e] >> SH], 1);
    __syncthreads();
    for (int i = threadIdx.x; i < NB_BKT; i += 256) {
        int v = lh[i];
        lbase[i] = v ? atomicAdd(&bcur[i], v) : 0;
        lh[i] = 0;
    }
    __syncthreads();
    for (int e = base + threadIdx.x; e < end; e += 256) {
        int c = col[e];
        int r = row[e];
        int b = c >> SH;
        int off = atomicAdd(&lh[b], 1);
        packed[lbase[b] + off] = ((unsigned long long)(unsigned)c << 32) | (unsigned)r;
    }
}

// P4: per-bucket per-node degree count, coalesced cnt write
__global__ void bucket_count(const unsigned long long* __restrict__ packed,
                             const int* __restrict__ bptr, int* __restrict__ cnt, int N) {
    int b = blockIdx.x;
    __shared__ int lcnt[128];
    if (threadIdx.x < 128) lcnt[threadIdx.x] = 0;
    __syncthreads();
    int s = bptr[b], e = bptr[b + 1];
    for (int i = s + threadIdx.x; i < e; i += 256) {
        int c = (int)(packed[i] >> 32);
        atomicAdd(&lcnt[c & 127], 1);
    }
    __syncthreads();
    int node = (b << SH) + threadIdx.x;
    if (threadIdx.x < 128 && node < N) cnt[node] = lcnt[threadIdx.x];
}

// P5: per-bucket placement into csr_row using LDS cursors (skip self slot)
__global__ void bucket_place(const unsigned long long* __restrict__ packed,
                             const int* __restrict__ bptr, const int* __restrict__ rowptr,
                             int* __restrict__ csr_row, int N) {
    int b = blockIdx.x;
    __shared__ int lcur[128];
    int node = (b << SH) + threadIdx.x;
    if (threadIdx.x < 128 && node < N) lcur[threadIdx.x] = rowptr[node] + 1;
    __syncthreads();
    int s = bptr[b], e = bptr[b + 1];
    for (int i = s + threadIdx.x; i < e; i += 256) {
        unsigned long long p = packed[i];
        int c = (int)(p >> 32);
        int r = (int)(p & 0xffffffffu);
        int pos = atomicAdd(&lcur[c & 127], 1);
        csr_row[pos] = r;
    }
}

// ======================= dinv + node scan ================================
__global__ void dinv_kernel(const int* __restrict__ cnt, float* __restrict__ dinv, int N) {
    int i = blockIdx.x * blockDim.x + threadIdx.x;
    if (i < N) dinv[i] = rsqrtf((float)cnt[i] + 1.0f);
}

__global__ void scan_blocks(const int* __restrict__ cnt, int* __restrict__ rowptr,
                            int* __restrict__ bsum, int N) {
    int t = threadIdx.x;
    int base = blockIdx.x * 512;
    int i0 = base + 2 * t, i1 = i0 + 1;
    int v0 = (i0 < N) ? cnt[i0] + 1 : 0;   // +1: self-edge slot
    int v1 = (i1 < N) ? cnt[i1] + 1 : 0;
    int s = v0 + v1;
    int lane = t & 63, wv = t >> 6;
    int incl = s;
#pragma unroll
    for (int off = 1; off < 64; off <<= 1) {
        int u = __shfl_up(incl, off, 64);
        if (lane >= off) incl += u;
    }
    __shared__ int wtot[4];
    if (lane == 63) wtot[wv] = incl;
    __syncthreads();
    int woff = 0;
    for (int w = 0; w < wv; w++) woff += wtot[w];
    int excl = woff + incl - s;
    if (i0 < N) rowptr[i0] = excl;
    if (i1 < N) rowptr[i1] = excl + v0;
    if (t == 255) bsum[blockIdx.x] = woff + incl;
}

__global__ void scan_bsums(int* __restrict__ bsum, int G) {
    int t = threadIdx.x;
    int v = (t < G) ? bsum[t] : 0;
    int lane = t & 63, wv = t >> 6;
    int incl = v;
#pragma unroll
    for (int off = 1; off < 64; off <<= 1) {
        int u = __shfl_up(incl, off, 64);
        if (lane >= off) incl += u;
    }
    __shared__ int wtot[4];
    if (lane == 63) wtot[wv] = incl;
    __syncthreads();
    int woff = 0;
    for (int w = 0; w < wv; w++) woff += wtot[w];
    if (t < G) bsum[t] = woff + incl - v;
}

// add block offsets, prefill self-edge
__global__ void scan_finish(int* __restrict__ rowptr, const int* __restrict__ bsum,
                            int* __restrict__ csr_row, int N) {
    int i = blockIdx.x * blockDim.x + threadIdx.x;
    if (i < N) {
        int v = rowptr[i] + bsum[i >> 9];
        rowptr[i] = v;
        csr_row[v] = i;        // self edge first in each segment
    }
    if (i == 0) rowptr[N] = NE + NN;
}

// ======================= x pad copy (21 -> stride 32) ====================
__global__ void padx_kernel(const float* __restrict__ x, float* __restrict__ xp, int N) {
    int idx = blockIdx.x * blockDim.x + threadIdx.x;
    if (idx >= N * 21) return;
    int n = idx / 21;
    int k = idx - n * 21;
    xp[n * 32 + k] = x[idx];
}

// ======================= pull gather (float4 rows) =======================
// row stride in floats = 4*LPN. blockDim = (LPN, NPB). weight = dinv[r]*dinv[node].
template <int LPN, bool BIAS, bool STORE21>
__global__ void gather4_kernel(const float4* __restrict__ h, const int* __restrict__ rowptr,
                               const int* __restrict__ csr_row, const float* __restrict__ dinv,
                               const float* __restrict__ bias, float* __restrict__ outp, int N) {
    int node = blockIdx.x * blockDim.y + threadIdx.y;
    if (node >= N) return;
    int l = threadIdx.x;
    int s = rowptr[node], e = rowptr[node + 1];
    float dn = dinv[node];
    float4 acc = make_float4(0.f, 0.f, 0.f, 0.f);
    int i = s;
    for (; i + 1 < e; i += 2) {
        int r0 = csr_row[i];
        int r1 = csr_row[i + 1];
        float w0 = dinv[r0] * dn;
        float w1 = dinv[r1] * dn;
        float4 a = h[(size_t)r0 * LPN + l];
        float4 c = h[(size_t)r1 * LPN + l];
        acc.x = fmaf(w0, a.x, acc.x); acc.y = fmaf(w0, a.y, acc.y);
        acc.z = fmaf(w0, a.z, acc.z); acc.w = fmaf(w0, a.w, acc.w);
        acc.x = fmaf(w1, c.x, acc.x); acc.y = fmaf(w1, c.y, acc.y);
        acc.z = fmaf(w1, c.z, acc.z); acc.w = fmaf(w1, c.w, acc.w);
    }
    if (i < e) {
        int r0 = csr_row[i];
        float w0 = dinv[r0] * dn;
        float4 a = h[(size_t)r0 * LPN + l];
        acc.x = fmaf(w0, a.x, acc.x); acc.y = fmaf(w0, a.y, acc.y);
        acc.z = fmaf(w0, a.z, acc.z); acc.w = fmaf(w0, a.w, acc.w);
    }
    if (STORE21) {
        int j = 4 * l;
        float v[4] = {acc.x, acc.y, acc.z, acc.w};
#pragma unroll
        for (int c = 0; c < 4; c++) {
            int jj = j + c;
            if (jj < 21) outp[(size_t)node * 21 + jj] = v[c] + (BIAS ? bias[jj] : 0.f);
        }
    } else {
        ((float4*)outp)[(size_t)node * LPN + l] = acc;
    }
}

// ======================= register-tiled GEMM =============================
template <int FIN, int FOUT, int FOUTP, int NT, int RJ, bool BIAS, bool RELU,
          int XSTRIDE, int OSTRIDE>
__global__ void gemm_tiled(const float* __restrict__ x, const float* __restrict__ W,
                           const float* __restrict__ b, float* __restrict__ out, int N) {
    constexpr int JG = FOUTP / RJ;
    constexpr int NG = 256 / JG;
    constexpr int RN = NT / NG;
    constexpr int XLD = FIN + 1;
    __shared__ float xs[NT * XLD];
    __shared__ float Ws[FIN * FOUTP];
    __shared__ float bs[FOUTP];
    const int t = threadIdx.x;
    const int node0 = blockIdx.x * NT;

    for (int i = t; i < FIN * FOUT; i += 256) {
        int k = i / FOUT;
        int j = i - k * FOUT;
        Ws[k * FOUTP + j] = W[i];
    }
    if (FOUTP > FOUT) {
        for (int i = t; i < FIN * (FOUTP - FOUT); i += 256) {
            int k = i / (FOUTP - FOUT);
            int j = i - k * (FOUTP - FOUT);
            Ws[k * FOUTP + FOUT + j] = 0.f;
        }
    }
    if (t < FOUTP) bs[t] = (BIAS && t < FOUT) ? b[t] : 0.f;

    if (FIN % 4 == 0) {
        constexpr int F4 = FIN / 4;
        for (int i = t; i < NT * F4; i += 256) {
            int n = i / F4;
            int kk = i - n * F4;
            int node = node0 + n;
            float4 v = (node < N) ? ((const float4*)x)[(size_t)node * (XSTRIDE / 4) + kk]
                                  : make_float4(0.f, 0.f, 0.f, 0.f);
            xs[n * XLD + 4 * kk + 0] = v.x;
            xs[n * XLD + 4 * kk + 1] = v.y;
            xs[n * XLD + 4 * kk + 2] = v.z;
            xs[n * XLD + 4 * kk + 3] = v.w;
        }
    } else {
        for (int i = t; i < NT * FIN; i += 256) {
            int n = i / FIN;
            int k = i - n * FIN;
            int node = node0 + n;
            xs[n * XLD + k] = (node < N) ? x[(size_t)node * XSTRIDE + k] : 0.f;
        }
    }
    __syncthreads();

    const int jg = t % JG;
    const int ng = t / JG;
    float acc[RN][RJ];
#pragma unroll
    for (int r = 0; r < RN; r++)
#pragma unroll
        for (int jj = 0; jj < RJ; jj++) acc[r][jj] = 0.f;

#pragma unroll 2
    for (int k = 0; k < FIN; k++) {
        float wv[RJ];
        if (RJ % 4 == 0) {
#pragma unroll
            for (int c = 0; c < RJ / 4; c++) {
                float4 w = *(const float4*)&Ws[k * FOUTP + jg * RJ + 4 * c];
                wv[4 * c + 0] = w.x; wv[4 * c + 1] = w.y;
                wv[4 * c + 2] = w.z; wv[4 * c + 3] = w.w;
            }
        } else {
#pragma unroll
            for (int c = 0; c < RJ / 2; c++) {
                float2 w = *(const float2*)&Ws[k * FOUTP + jg * RJ + 2 * c];
                wv[2 * c + 0] = w.x; wv[2 * c + 1] = w.y;
            }
        }
        float xv[RN];
#pragma unroll
        for (int r = 0; r < RN; r++) xv[r] = xs[(ng * RN + r) * XLD + k];
#pragma unroll
        for (int r = 0; r < RN; r++)
#pragma unroll
            for (int jj = 0; jj < RJ; jj++) acc[r][jj] = fmaf(xv[r], wv[jj], acc[r][jj]);
    }

#pragma unroll
    for (int r = 0; r < RN; r++) {
        int node = node0 + ng * RN + r;
        if (node >= N) continue;
        float* orow = out + (size_t)node * OSTRIDE + jg * RJ;
#pragma unroll
        for (int jj = 0; jj < RJ; jj++) {
            float v = acc[r][jj] + bs[jg * RJ + jj];
            if (RELU) v = fmaxf(v, 0.f);
            acc[r][jj] = v;
        }
        if (RJ % 4 == 0 && OSTRIDE % 4 == 0) {
#pragma unroll
            for (int c = 0; c < RJ / 4; c++) {
                *(float4*)&orow[4 * c] =
                    make_float4(acc[r][4 * c], acc[r][4 * c + 1], acc[r][4 * c + 2], acc[r][4 * c + 3]);
            }
        } else {
#pragma unroll
            for (int jj = 0; jj < RJ; jj++) orow[jj] = acc[r][jj];
        }
    }
}

// ======================= launch ==========================================
extern "C" void kernel_launch(void* const* d_in, const int* in_sizes, int n_in,
                              void* d_out, int out_size, void* d_ws, size_t ws_size,
                              hipStream_t stream) {
    const float* x  = (const float*)d_in[0];
    const int*   ei = (const int*)d_in[1];
    const float* W1 = (const float*)d_in[2]; const float* b1 = (const float*)d_in[3];
    const float* W2 = (const float*)d_in[4]; const float* b2 = (const float*)d_in[5];
    const float* W3 = (const float*)d_in[6]; const float* b3 = (const float*)d_in[7];
    const float* W4 = (const float*)d_in[8]; const float* b4 = (const float*)d_in[9];
    const int* row = ei;
    const int* col = ei + NE;
    float* out = (float*)d_out;

    // workspace layout (floats)
    float* A      = (float*)d_ws;                  // N x 128
    float* B      = A + (size_t)NN * 128;          // N x 128 (also padded-x staging)
    float* dinv   = B + (size_t)NN * 128;          // N
    int*   cnt    = (int*)(dinv + NN);             // N
    int*   rowptr = cnt + NN;                      // N+1
    int*   csr_row= rowptr + NN + 1;               // E + N
    int*   bsum   = csr_row + NE + NN;             // 256
    int*   bcnt   = bsum + 256;                    // NB_BKT
    int*   bptr   = bcnt + NB_BKT;                 // NB_BKT+1
    int*   bcur   = bptr + NB_BKT + 1;             // NB_BKT
    // packed (col,row) u64 aliases A: only live before layer-1 gather writes A
    unsigned long long* packed = (unsigned long long*)A;

    const int BS = 256;
    const int SCAN_G = cdiv(NN, 512);   // 196
    const int NCH = cdiv(NE, CHUNK);    // 196

    // ---- bucketed CSR build ----
    hipMemsetAsync(bcnt, 0, NB_BKT * sizeof(int), stream);
    bucket_hist<<<NCH, 256, 0, stream>>>(col, bcnt, NE);
    bucket_scan<<<1, 256, 0, stream>>>(bcnt, bptr, bcur);
    partition_kernel<<<NCH, 256, 0, stream>>>(row, col, bcur, packed, NE);
    bucket_count<<<NB_BKT, 256, 0, stream>>>(packed, bptr, cnt, NN);
    dinv_kernel<<<cdiv(NN, BS), BS, 0, stream>>>(cnt, dinv, NN);
    scan_blocks<<<SCAN_G, 256, 0, stream>>>(cnt, rowptr, bsum, NN);
    scan_bsums<<<1, 256, 0, stream>>>(bsum, SCAN_G);
    scan_finish<<<cdiv(NN, BS), BS, 0, stream>>>(rowptr, bsum, csr_row, NN);
    bucket_place<<<NB_BKT, 256, 0, stream>>>(packed, bptr, rowptr, csr_row, NN);

    // ---- pad x into B (stride 32) ----
    padx_kernel<<<cdiv((long long)NN * 21, BS), BS, 0, stream>>>(x, B, NN);

    // ---- Layer 1: gather(x32) [B->A], gemm 21->32 +b relu [A->B, stride 32] ----
    {
        dim3 blk(8, 32);
        gather4_kernel<8, false, false><<<cdiv(NN, 32), blk, 0, stream>>>(
            (const float4*)B, rowptr, csr_row, dinv, nullptr, A, NN);
        gemm_tiled<21, 32, 32, 64, 8, true, true, 32, 32><<<cdiv(NN, 64), 256, 0, stream>>>(
            A, W1, b1, B, NN);
    }
    // ---- Layer 2: gather(h1) [B->A], gemm 32->64 +b relu [A->B, stride 64] ----
    {
        dim3 blk(8, 32);
        gather4_kernel<8, false, false><<<cdiv(NN, 32), blk, 0, stream>>>(
            (const float4*)B, rowptr, csr_row, dinv, nullptr, A, NN);
        gemm_tiled<32, 64, 64, 64, 8, true, true, 32, 64><<<cdiv(NN, 64), 256, 0, stream>>>(
            A, W2, b2, B, NN);
    }
    // ---- Layer 3: gather(h2) [B->A], gemm 64->128 +b relu [A->B, stride 128] ----
    {
        dim3 blk(16, 16);
        gather4_kernel<16, false, false><<<cdiv(NN, 16), blk, 0, stream>>>(
            (const float4*)B, rowptr, csr_row, dinv, nullptr, A, NN);
        gemm_tiled<64, 128, 128, 64, 8, true, true, 64, 128><<<cdiv(NN, 64), 256, 0, stream>>>(
            A, W3, b3, B, NN);
    }
    // ---- Layer 4: gemm 128->21 [B->A, stride 32], gather+b4 [A->out, stride 21] ----
    {
        gemm_tiled<128, 21, 24, 64, 6, false, false, 128, 32><<<cdiv(NN, 64), 256, 0, stream>>>(
            B, W4, nullptr, A, NN);
        dim3 blk(8, 32);
        gather4_kernel<8, true, true><<<cdiv(NN, 32), blk, 0, stream>>>(
            (const float4*)A, rowptr, csr_row, dinv, b4, out, NN);
    }
}

// Round 6
// 408.157 us; speedup vs baseline: 1.4201x; 1.0740x over previous
//
#include <hip/hip_runtime.h>

#define NN 100000
#define NE 1600000
#define SH 7
#define NB_BKT 782        // ceil(100000/128)
#define CHUNK 8192

static inline int cdiv(long long a, int b) { return (int)((a + b - 1) / b); }

// ======================= bucketed CSR build ==============================
__global__ void bucket_hist(const int* __restrict__ col, int* __restrict__ bcnt, int E) {
    __shared__ int lh[NB_BKT];
    for (int i = threadIdx.x; i < NB_BKT; i += 256) lh[i] = 0;
    __syncthreads();
    int base = blockIdx.x * CHUNK;
    int end = min(base + CHUNK, E);
    for (int e = base + threadIdx.x; e < end; e += 256) atomicAdd(&lh[col[e] >> SH], 1);
    __syncthreads();
    for (int i = threadIdx.x; i < NB_BKT; i += 256)
        if (lh[i]) atomicAdd(&bcnt[i], lh[i]);
}

__global__ void bucket_scan(const int* __restrict__ bcnt, int* __restrict__ bptr,
                            int* __restrict__ bcur) {
    int t = threadIdx.x;
    int v[4];
    int base = 4 * t;
    int s = 0;
#pragma unroll
    for (int c = 0; c < 4; c++) {
        int i = base + c;
        v[c] = (i < NB_BKT) ? bcnt[i] : 0;
        s += v[c];
    }
    int lane = t & 63, wv = t >> 6;
    int incl = s;
#pragma unroll
    for (int off = 1; off < 64; off <<= 1) {
        int u = __shfl_up(incl, off, 64);
        if (lane >= off) incl += u;
    }
    __shared__ int wtot[4];
    if (lane == 63) wtot[wv] = incl;
    __syncthreads();
    int woff = 0;
    for (int w = 0; w < wv; w++) woff += wtot[w];
    int excl = woff + incl - s;
#pragma unroll
    for (int c = 0; c < 4; c++) {
        int i = base + c;
        if (i < NB_BKT) { bptr[i] = excl; bcur[i] = excl; }
        excl += v[c];
    }
    if (t == 255) bptr[NB_BKT] = woff + incl;
}

__global__ void partition_kernel(const int* __restrict__ row, const int* __restrict__ col,
                                 int* __restrict__ bcur,
                                 unsigned long long* __restrict__ packed, int E) {
    __shared__ int lh[NB_BKT];
    __shared__ int lbase[NB_BKT];
    for (int i = threadIdx.x; i < NB_BKT; i += 256) lh[i] = 0;
    __syncthreads();
    int base = blockIdx.x * CHUNK;
    int end = min(base + CHUNK, E);
    for (int e = base + threadIdx.x; e < end; e += 256) atomicAdd(&lh[col[e] >> SH], 1);
    __syncthreads();
    for (int i = threadIdx.x; i < NB_BKT; i += 256) {
        int v = lh[i];
        lbase[i] = v ? atomicAdd(&bcur[i], v) : 0;
        lh[i] = 0;
    }
    __syncthreads();
    for (int e = base + threadIdx.x; e < end; e += 256) {
        int c = col[e];
        int r = row[e];
        int b = c >> SH;
        int off = atomicAdd(&lh[b], 1);
        packed[lbase[b] + off] = ((unsigned long long)(unsigned)c << 32) | (unsigned)r;
    }
}

__global__ void bucket_count(const unsigned long long* __restrict__ packed,
                             const int* __restrict__ bptr, int* __restrict__ cnt, int N) {
    int b = blockIdx.x;
    __shared__ int lcnt[128];
    if (threadIdx.x < 128) lcnt[threadIdx.x] = 0;
    __syncthreads();
    int s = bptr[b], e = bptr[b + 1];
    for (int i = s + threadIdx.x; i < e; i += 256) {
        int c = (int)(packed[i] >> 32);
        atomicAdd(&lcnt[c & 127], 1);
    }
    __syncthreads();
    int node = (b << SH) + threadIdx.x;
    if (threadIdx.x < 128 && node < N) cnt[node] = lcnt[threadIdx.x];
}

__global__ void bucket_place(const unsigned long long* __restrict__ packed,
                             const int* __restrict__ bptr, const int* __restrict__ rowptr,
                             int* __restrict__ csr_row, int N) {
    int b = blockIdx.x;
    __shared__ int lcur[128];
    int node = (b << SH) + threadIdx.x;
    if (threadIdx.x < 128 && node < N) lcur[threadIdx.x] = rowptr[node] + 1;
    __syncthreads();
    int s = bptr[b], e = bptr[b + 1];
    for (int i = s + threadIdx.x; i < e; i += 256) {
        unsigned long long p = packed[i];
        int c = (int)(p >> 32);
        int r = (int)(p & 0xffffffffu);
        int pos = atomicAdd(&lcur[c & 127], 1);
        csr_row[pos] = r;
    }
}

// ======================= node scan (+dinv fused) =========================
__global__ void scan_blocks(const int* __restrict__ cnt, int* __restrict__ rowptr,
                            int* __restrict__ bsum, float* __restrict__ dinv, int N) {
    int t = threadIdx.x;
    int base = blockIdx.x * 512;
    int i0 = base + 2 * t, i1 = i0 + 1;
    int v0 = (i0 < N) ? cnt[i0] + 1 : 0;   // +1: self-edge slot (== deg+1)
    int v1 = (i1 < N) ? cnt[i1] + 1 : 0;
    if (i0 < N) dinv[i0] = rsqrtf((float)v0);
    if (i1 < N) dinv[i1] = rsqrtf((float)v1);
    int s = v0 + v1;
    int lane = t & 63, wv = t >> 6;
    int incl = s;
#pragma unroll
    for (int off = 1; off < 64; off <<= 1) {
        int u = __shfl_up(incl, off, 64);
        if (lane >= off) incl += u;
    }
    __shared__ int wtot[4];
    if (lane == 63) wtot[wv] = incl;
    __syncthreads();
    int woff = 0;
    for (int w = 0; w < wv; w++) woff += wtot[w];
    int excl = woff + incl - s;
    if (i0 < N) rowptr[i0] = excl;
    if (i1 < N) rowptr[i1] = excl + v0;
    if (t == 255) bsum[blockIdx.x] = woff + incl;
}

__global__ void scan_bsums(int* __restrict__ bsum, int G) {
    int t = threadIdx.x;
    int v = (t < G) ? bsum[t] : 0;
    int lane = t & 63, wv = t >> 6;
    int incl = v;
#pragma unroll
    for (int off = 1; off < 64; off <<= 1) {
        int u = __shfl_up(incl, off, 64);
        if (lane >= off) incl += u;
    }
    __shared__ int wtot[4];
    if (lane == 63) wtot[wv] = incl;
    __syncthreads();
    int woff = 0;
    for (int w = 0; w < wv; w++) woff += wtot[w];
    if (t < G) bsum[t] = woff + incl - v;
}

__global__ void scan_finish(int* __restrict__ rowptr, const int* __restrict__ bsum,
                            int* __restrict__ csr_row, int N) {
    int i = blockIdx.x * blockDim.x + threadIdx.x;
    if (i < N) {
        int v = rowptr[i] + bsum[i >> 9];
        rowptr[i] = v;
        csr_row[v] = i;        // self edge first in each segment
    }
    if (i == 0) rowptr[N] = NE + NN;
}

// ======================= x pad copy (21 -> stride 32, zero pad) ==========
__global__ void padx_kernel(const float* __restrict__ x, float* __restrict__ xp, int N) {
    int idx = blockIdx.x * blockDim.x + threadIdx.x;
    if (idx >= N * 32) return;
    int n = idx >> 5;
    int k = idx & 31;
    xp[idx] = (k < 21) ? x[n * 21 + k] : 0.f;
}

// ======================= fused gather + GEMM =============================
// Phase 1: gather F_in features of NT nodes into LDS (LPN lanes/node, float4).
// Phase 2: register-tiled GEMM from LDS (+bias, relu), coalesced store.
template <int LPN, int FIN, int FOUT, int RJ, int OSTRIDE>
__global__ __launch_bounds__(512) void gather_gemm(
    const float4* __restrict__ h, const int* __restrict__ rowptr,
    const int* __restrict__ csr_row, const float* __restrict__ dinv,
    const float* __restrict__ W, const float* __restrict__ b,
    float* __restrict__ out, int N) {
    constexpr int NT = 512 / LPN;        // nodes per block
    constexpr int FINP = 4 * LPN;        // gathered row width (>= FIN)
    constexpr int XLD = FINP + 1;
    constexpr int JG = FOUT / RJ;        // must satisfy 512/JG == NT
    __shared__ float xs[NT * XLD];
    __shared__ float Ws[FIN * FOUT];
    __shared__ float bs[FOUT];
    const int t = threadIdx.x;

    for (int i = t; i < FIN * FOUT; i += 512) Ws[i] = W[i];
    if (t < FOUT) bs[t] = b[t];

    // ---- gather phase ----
    const int l = t % LPN;
    const int ny = t / LPN;
    const int node = blockIdx.x * NT + ny;
    float4 acc = make_float4(0.f, 0.f, 0.f, 0.f);
    if (node < N) {
        int s = rowptr[node], e = rowptr[node + 1];
        float dn = dinv[node];
        int i = s;
        for (; i + 3 < e; i += 4) {
            int r0 = csr_row[i], r1 = csr_row[i + 1], r2 = csr_row[i + 2], r3 = csr_row[i + 3];
            float w0 = dinv[r0] * dn, w1 = dinv[r1] * dn, w2 = dinv[r2] * dn, w3 = dinv[r3] * dn;
            float4 a0 = h[(size_t)r0 * LPN + l];
            float4 a1 = h[(size_t)r1 * LPN + l];
            float4 a2 = h[(size_t)r2 * LPN + l];
            float4 a3 = h[(size_t)r3 * LPN + l];
            acc.x = fmaf(w0, a0.x, acc.x); acc.y = fmaf(w0, a0.y, acc.y);
            acc.z = fmaf(w0, a0.z, acc.z); acc.w = fmaf(w0, a0.w, acc.w);
            acc.x = fmaf(w1, a1.x, acc.x); acc.y = fmaf(w1, a1.y, acc.y);
            acc.z = fmaf(w1, a1.z, acc.z); acc.w = fmaf(w1, a1.w, acc.w);
            acc.x = fmaf(w2, a2.x, acc.x); acc.y = fmaf(w2, a2.y, acc.y);
            acc.z = fmaf(w2, a2.z, acc.z); acc.w = fmaf(w2, a2.w, acc.w);
            acc.x = fmaf(w3, a3.x, acc.x); acc.y = fmaf(w3, a3.y, acc.y);
            acc.z = fmaf(w3, a3.z, acc.z); acc.w = fmaf(w3, a3.w, acc.w);
        }
        for (; i < e; i++) {
            int r0 = csr_row[i];
            float w0 = dinv[r0] * dn;
            float4 a0 = h[(size_t)r0 * LPN + l];
            acc.x = fmaf(w0, a0.x, acc.x); acc.y = fmaf(w0, a0.y, acc.y);
            acc.z = fmaf(w0, a0.z, acc.z); acc.w = fmaf(w0, a0.w, acc.w);
        }
    }
    xs[ny * XLD + 4 * l + 0] = acc.x;
    xs[ny * XLD + 4 * l + 1] = acc.y;
    xs[ny * XLD + 4 * l + 2] = acc.z;
    xs[ny * XLD + 4 * l + 3] = acc.w;
    __syncthreads();

    // ---- GEMM phase ----
    const int jg = t % JG;
    const int ng = t / JG;           // node index in tile (== NT groups)
    float r[RJ];
#pragma unroll
    for (int jj = 0; jj < RJ; jj++) r[jj] = 0.f;
#pragma unroll 4
    for (int k = 0; k < FIN; k++) {
        float xv = xs[ng * XLD + k];
#pragma unroll
        for (int jj = 0; jj < RJ; jj++)
            r[jj] = fmaf(xv, Ws[k * FOUT + jg * RJ + jj], r[jj]);
    }
    int onode = blockIdx.x * NT + ng;
    if (onode < N) {
        float* orow = out + (size_t)onode * OSTRIDE + jg * RJ;
#pragma unroll
        for (int jj = 0; jj < RJ; jj++) r[jj] = fmaxf(r[jj] + bs[jg * RJ + jj], 0.f);
#pragma unroll
        for (int c = 0; c < RJ / 4; c++)
            *(float4*)&orow[4 * c] = make_float4(r[4 * c], r[4 * c + 1], r[4 * c + 2], r[4 * c + 3]);
    }
}

// ======================= standalone gather (layer 4) =====================
template <int LPN, bool BIAS, bool STORE21>
__global__ void gather4_kernel(const float4* __restrict__ h, const int* __restrict__ rowptr,
                               const int* __restrict__ csr_row, const float* __restrict__ dinv,
                               const float* __restrict__ bias, float* __restrict__ outp, int N) {
    int node = blockIdx.x * blockDim.y + threadIdx.y;
    if (node >= N) return;
    int l = threadIdx.x;
    int s = rowptr[node], e = rowptr[node + 1];
    float dn = dinv[node];
    float4 acc = make_float4(0.f, 0.f, 0.f, 0.f);
    int i = s;
    for (; i + 3 < e; i += 4) {
        int r0 = csr_row[i], r1 = csr_row[i + 1], r2 = csr_row[i + 2], r3 = csr_row[i + 3];
        float w0 = dinv[r0] * dn, w1 = dinv[r1] * dn, w2 = dinv[r2] * dn, w3 = dinv[r3] * dn;
        float4 a0 = h[(size_t)r0 * LPN + l];
        float4 a1 = h[(size_t)r1 * LPN + l];
        float4 a2 = h[(size_t)r2 * LPN + l];
        float4 a3 = h[(size_t)r3 * LPN + l];
        acc.x = fmaf(w0, a0.x, acc.x); acc.y = fmaf(w0, a0.y, acc.y);
        acc.z = fmaf(w0, a0.z, acc.z); acc.w = fmaf(w0, a0.w, acc.w);
        acc.x = fmaf(w1, a1.x, acc.x); acc.y = fmaf(w1, a1.y, acc.y);
        acc.z = fmaf(w1, a1.z, acc.z); acc.w = fmaf(w1, a1.w, acc.w);
        acc.x = fmaf(w2, a2.x, acc.x); acc.y = fmaf(w2, a2.y, acc.y);
        acc.z = fmaf(w2, a2.z, acc.z); acc.w = fmaf(w2, a2.w, acc.w);
        acc.x = fmaf(w3, a3.x, acc.x); acc.y = fmaf(w3, a3.y, acc.y);
        acc.z = fmaf(w3, a3.z, acc.z); acc.w = fmaf(w3, a3.w, acc.w);
    }
    for (; i < e; i++) {
        int r0 = csr_row[i];
        float w0 = dinv[r0] * dn;
        float4 a0 = h[(size_t)r0 * LPN + l];
        acc.x = fmaf(w0, a0.x, acc.x); acc.y = fmaf(w0, a0.y, acc.y);
        acc.z = fmaf(w0, a0.z, acc.z); acc.w = fmaf(w0, a0.w, acc.w);
    }
    if (STORE21) {
        int j = 4 * l;
        float v[4] = {acc.x, acc.y, acc.z, acc.w};
#pragma unroll
        for (int c = 0; c < 4; c++) {
            int jj = j + c;
            if (jj < 21) outp[(size_t)node * 21 + jj] = v[c] + (BIAS ? bias[jj] : 0.f);
        }
    } else {
        ((float4*)outp)[(size_t)node * LPN + l] = acc;
    }
}

// ======================= register-tiled GEMM (layer 4) ===================
template <int FIN, int FOUT, int FOUTP, int NT, int RJ, bool BIAS, bool RELU,
          int XSTRIDE, int OSTRIDE>
__global__ void gemm_tiled(const float* __restrict__ x, const float* __restrict__ W,
                           const float* __restrict__ b, float* __restrict__ out, int N) {
    constexpr int JG = FOUTP / RJ;
    constexpr int NG = 256 / JG;
    constexpr int RN = NT / NG;
    constexpr int XLD = FIN + 1;
    __shared__ float xs[NT * XLD];
    __shared__ float Ws[FIN * FOUTP];
    __shared__ float bs[FOUTP];
    const int t = threadIdx.x;
    const int node0 = blockIdx.x * NT;

    for (int i = t; i < FIN * FOUT; i += 256) {
        int k = i / FOUT;
        int j = i - k * FOUT;
        Ws[k * FOUTP + j] = W[i];
    }
    if (FOUTP > FOUT) {
        for (int i = t; i < FIN * (FOUTP - FOUT); i += 256) {
            int k = i / (FOUTP - FOUT);
            int j = i - k * (FOUTP - FOUT);
            Ws[k * FOUTP + FOUT + j] = 0.f;
        }
    }
    if (t < FOUTP) bs[t] = (BIAS && t < FOUT) ? b[t] : 0.f;

    if (FIN % 4 == 0) {
        constexpr int F4 = FIN / 4;
        for (int i = t; i < NT * F4; i += 256) {
            int n = i / F4;
            int kk = i - n * F4;
            int node = node0 + n;
            float4 v = (node < N) ? ((const float4*)x)[(size_t)node * (XSTRIDE / 4) + kk]
                                  : make_float4(0.f, 0.f, 0.f, 0.f);
            xs[n * XLD + 4 * kk + 0] = v.x;
            xs[n * XLD + 4 * kk + 1] = v.y;
            xs[n * XLD + 4 * kk + 2] = v.z;
            xs[n * XLD + 4 * kk + 3] = v.w;
        }
    } else {
        for (int i = t; i < NT * FIN; i += 256) {
            int n = i / FIN;
            int k = i - n * FIN;
            int node = node0 + n;
            xs[n * XLD + k] = (node < N) ? x[(size_t)node * XSTRIDE + k] : 0.f;
        }
    }
    __syncthreads();

    const int jg = t % JG;
    const int ng = t / JG;
    float acc[RN][RJ];
#pragma unroll
    for (int r = 0; r < RN; r++)
#pragma unroll
        for (int jj = 0; jj < RJ; jj++) acc[r][jj] = 0.f;

#pragma unroll 2
    for (int k = 0; k < FIN; k++) {
        float wv[RJ];
#pragma unroll
        for (int c = 0; c < RJ / 2; c++) {
            float2 w = *(const float2*)&Ws[k * FOUTP + jg * RJ + 2 * c];
            wv[2 * c + 0] = w.x; wv[2 * c + 1] = w.y;
        }
        float xv[RN];
#pragma unroll
        for (int r = 0; r < RN; r++) xv[r] = xs[(ng * RN + r) * XLD + k];
#pragma unroll
        for (int r = 0; r < RN; r++)
#pragma unroll
            for (int jj = 0; jj < RJ; jj++) acc[r][jj] = fmaf(xv[r], wv[jj], acc[r][jj]);
    }

#pragma unroll
    for (int r = 0; r < RN; r++) {
        int node = node0 + ng * RN + r;
        if (node >= N) continue;
        float* orow = out + (size_t)node * OSTRIDE + jg * RJ;
#pragma unroll
        for (int jj = 0; jj < RJ; jj++) {
            float v = acc[r][jj] + bs[jg * RJ + jj];
            if (RELU) v = fmaxf(v, 0.f);
            orow[jj] = v;
        }
    }
}

// ======================= launch ==========================================
extern "C" void kernel_launch(void* const* d_in, const int* in_sizes, int n_in,
                              void* d_out, int out_size, void* d_ws, size_t ws_size,
                              hipStream_t stream) {
    const float* x  = (const float*)d_in[0];
    const int*   ei = (const int*)d_in[1];
    const float* W1 = (const float*)d_in[2]; const float* b1 = (const float*)d_in[3];
    const float* W2 = (const float*)d_in[4]; const float* b2 = (const float*)d_in[5];
    const float* W3 = (const float*)d_in[6]; const float* b3 = (const float*)d_in[7];
    const float* W4 = (const float*)d_in[8]; const float* b4 = (const float*)d_in[9];
    const int* row = ei;
    const int* col = ei + NE;
    float* out = (float*)d_out;

    // workspace layout (floats)
    float* A      = (float*)d_ws;                  // N x 128
    float* B      = A + (size_t)NN * 128;          // N x 128
    float* dinv   = B + (size_t)NN * 128;          // N
    int*   cnt    = (int*)(dinv + NN);             // N
    int*   rowptr = cnt + NN;                      // N+1
    int*   csr_row= rowptr + NN + 1;               // E + N
    int*   bsum   = csr_row + NE + NN;             // 256
    int*   bcnt   = bsum + 256;                    // NB_BKT
    int*   bptr   = bcnt + NB_BKT;                 // NB_BKT+1
    int*   bcur   = bptr + NB_BKT + 1;             // NB_BKT
    // packed (col,row) u64 aliases A: dead before layer-1 writes A
    unsigned long long* packed = (unsigned long long*)A;

    const int BS = 256;
    const int SCAN_G = cdiv(NN, 512);   // 196
    const int NCH = cdiv(NE, CHUNK);    // 196

    // ---- bucketed CSR build ----
    hipMemsetAsync(bcnt, 0, NB_BKT * sizeof(int), stream);
    bucket_hist<<<NCH, 256, 0, stream>>>(col, bcnt, NE);
    bucket_scan<<<1, 256, 0, stream>>>(bcnt, bptr, bcur);
    partition_kernel<<<NCH, 256, 0, stream>>>(row, col, bcur, packed, NE);
    bucket_count<<<NB_BKT, 256, 0, stream>>>(packed, bptr, cnt, NN);
    scan_blocks<<<SCAN_G, 256, 0, stream>>>(cnt, rowptr, bsum, dinv, NN);
    scan_bsums<<<1, 256, 0, stream>>>(bsum, SCAN_G);
    scan_finish<<<cdiv(NN, BS), BS, 0, stream>>>(rowptr, bsum, csr_row, NN);
    bucket_place<<<NB_BKT, 256, 0, stream>>>(packed, bptr, rowptr, csr_row, NN);

    // ---- pad x into B (stride 32, zero-padded) ----
    padx_kernel<<<cdiv((long long)NN * 32, BS), BS, 0, stream>>>(x, B, NN);

    // ---- L1: fused gather(x32)+gemm 21->32 +b relu : B -> A (stride 32) ----
    gather_gemm<8, 21, 32, 4, 32><<<cdiv(NN, 64), 512, 0, stream>>>(
        (const float4*)B, rowptr, csr_row, dinv, W1, b1, A, NN);
    // ---- L2: fused gather(h1)+gemm 32->64 +b relu : A -> B (stride 64) ----
    gather_gemm<8, 32, 64, 8, 64><<<cdiv(NN, 64), 512, 0, stream>>>(
        (const float4*)A, rowptr, csr_row, dinv, W2, b2, B, NN);
    // ---- L3: fused gather(h2)+gemm 64->128 +b relu : B -> A (stride 128) ----
    gather_gemm<16, 64, 128, 8, 128><<<cdiv(NN, 32), 512, 0, stream>>>(
        (const float4*)B, rowptr, csr_row, dinv, W3, b3, A, NN);
    // ---- L4: gemm 128->21 (A -> B, stride 32), gather+b4 (B -> out) ----
    gemm_tiled<128, 21, 24, 64, 6, false, false, 128, 32><<<cdiv(NN, 64), 256, 0, stream>>>(
        A, W4, nullptr, B, NN);
    {
        dim3 blk(8, 32);
        gather4_kernel<8, true, true><<<cdiv(NN, 32), blk, 0, stream>>>(
            (const float4*)B, rowptr, csr_row, dinv, b4, out, NN);
    }
}